// Round 8
// baseline (230.214 us; speedup 1.0000x reference)
//
#include <hip/hip_runtime.h>
#include <stdint.h>

// UnaryLinear (UnarySim stochastic linear), one clock, batch=1.
// out[o] = (acc[o] + sum_i f(i,o) + b_bit[o]) >= acc_bound
//   f = x[i] ? (w[o,i] >= brev8(rwi[o,i])) : !(w[o,i] >= brev8(rwii[o,i]))
// Sobol closed form rng[i] == bitreverse8(i): verified R4 (absmax = 0).
//
// R4-R7 lesson: ~2.6 TB/s wall is MLP-bound and the VGPR load path cannot be
// deepened (compiler sinks batched loads (R6) or scratch-spills asm outputs
// (R7)). Switch to global_load_lds: DMA global->LDS with NO VGPR destination;
// in-flight depth lives in the vmcnt queue. 48KB staged per block, all 36
// wave-level 1KB DMAs issued back-to-back before any wait.

constexpr int IN_F  = 4096;
constexpr int OUT_F = 4096;

__device__ __forceinline__ float contrib(float w, int ii, int vi, float xf) {
    const float r  = (float)(__brev((unsigned)ii) >> 24);
    const float ri = (float)(__brev((unsigned)vi) >> 24);
    return (xf != 0.0f) ? ((w >= r) ? 1.0f : 0.0f)
                        : ((w >= ri) ? 0.0f : 1.0f);
}

#define GLOAD_LDS16(gp, lp)                                                  \
    __builtin_amdgcn_global_load_lds(                                        \
        (const __attribute__((address_space(1))) void*)(gp),                 \
        (__attribute__((address_space(3))) void*)(lp), 16, 0, 0)

__global__ __launch_bounds__(256) void unary_linear_kernel(
    const float* __restrict__ x,            // [IN_F] in {0,1}
    const float* __restrict__ buf_wght,     // [OUT_F, IN_F]
    const float* __restrict__ buf_bias,     // [OUT_F]
    const float* __restrict__ acc,          // [OUT_F]
    const float* __restrict__ acc_bound,    // [1] = IN_F+1
    const int*   __restrict__ rng_wght_idx,     // [OUT_F, IN_F] in [0,256)
    const int*   __restrict__ rng_bias_idx,     // [OUT_F]
    const int*   __restrict__ rng_wght_idx_inv, // [OUT_F, IN_F]
    float*       __restrict__ out)          // [OUT_F]
{
    const int row  = blockIdx.x;
    const int tid  = threadIdx.x;           // 0..255
    const int wave = tid >> 6;
    const int lane = tid & 63;

    __shared__ float lds_w[IN_F];           // 16 KB
    __shared__ int   lds_i[IN_F];           // 16 KB
    __shared__ int   lds_v[IN_F];           // 16 KB
    __shared__ float wsum[4];

    const char* wrow = (const char*)(buf_wght         + (size_t)row * IN_F);
    const char* irow = (const char*)(rng_wght_idx     + (size_t)row * IN_F);
    const char* vrow = (const char*)(rng_wght_idx_inv + (size_t)row * IN_F);

    // ---- DMA stage: wave w fills chunks [4w, 4w+4) of each array.
    // Each GLOAD_LDS16: 64 lanes x 16B = 1KB contiguous, LDS dest is
    // wave-uniform base + lane*16 (linear — matches global layout).
    // 12 DMAs/wave issued back-to-back, no VGPR results to spill.
    #pragma unroll
    for (int c = 0; c < 4; ++c) {
        const int ch   = wave * 4 + c;        // 0..15
        const int goff = ch * 1024 + lane * 16;
        const int loff = ch * 1024;
        GLOAD_LDS16(wrow + goff, (char*)lds_w + loff);
        GLOAD_LDS16(irow + goff, (char*)lds_i + loff);
        GLOAD_LDS16(vrow + goff, (char*)lds_v + loff);
    }

    __syncthreads();   // drains vmcnt(0): all 48KB resident before compute

    // ---- compute: element e = c*256 + tid. Lane-stride 4B LDS reads ->
    // 2 lanes/bank = conflict-free (m136). x is 16KB, L2/L3-hot: read global.
    float sum = 0.0f;
    #pragma unroll
    for (int c = 0; c < 16; ++c) {
        const int e = c * 256 + tid;
        sum += contrib(lds_w[e], lds_i[e], lds_v[e], x[e]);
    }

    // wave-level butterfly reduce (64 lanes)
    #pragma unroll
    for (int off = 32; off > 0; off >>= 1)
        sum += __shfl_down(sum, off);

    if (lane == 0) wsum[wave] = sum;
    __syncthreads();

    if (tid == 0) {
        const float rb = (float)(__brev((unsigned)rng_bias_idx[row]) >> 24);
        const float b_bit = (buf_bias[row] >= rb) ? 1.0f : 0.0f;
        const float total = acc[row] + wsum[0] + wsum[1] + wsum[2] + wsum[3] + b_bit;
        out[row] = (total >= acc_bound[0]) ? 1.0f : 0.0f;
    }
}

extern "C" void kernel_launch(void* const* d_in, const int* in_sizes, int n_in,
                              void* d_out, int out_size, void* d_ws, size_t ws_size,
                              hipStream_t stream)
{
    // setup_inputs() order:
    // 0:x 1:buf_wght 2:buf_bias 3:rng 4:acc 5:acc_bound
    // 6:rng_wght_idx 7:rng_bias_idx 8:rng_wght_idx_inv
    const float* x         = (const float*)d_in[0];
    const float* buf_wght  = (const float*)d_in[1];
    const float* buf_bias  = (const float*)d_in[2];
    // d_in[3] = rng table — unused (closed form: rng[i] == bitreverse8(i))
    const float* acc       = (const float*)d_in[4];
    const float* acc_bound = (const float*)d_in[5];
    const int*   rwi       = (const int*)d_in[6];
    const int*   rbi       = (const int*)d_in[7];
    const int*   rwii      = (const int*)d_in[8];
    float* out = (float*)d_out;

    dim3 grid(OUT_F);       // 4096 blocks: 1 row per block, 3 blocks/CU (LDS)
    dim3 block(256);
    hipLaunchKernelGGL(unary_linear_kernel, grid, block, 0, stream,
                       x, buf_wght, buf_bias, acc, acc_bound,
                       rwi, rbi, rwii, out);
}

// Round 10
// 195.847 us; speedup vs baseline: 1.1755x; 1.1755x over previous
//
#include <hip/hip_runtime.h>
#include <stdint.h>

// UnaryLinear (UnarySim stochastic linear), one clock, batch=1.
// out[o] = (acc[o] + sum_i f(i,o) + b_bit[o]) >= acc_bound
//   f = x[i] ? (w[o,i] >= brev8(rwi[o,i])) : !(w[o,i] >= brev8(rwii[o,i]))
// Sobol closed form rng[i] == bitreverse8(i): verified R4 (absmax = 0).
//
// R4-R8: five schedules pinned at 2.0-2.7 TB/s; MLP-starvation refuted
// (R8 had ~144KB/CU in flight, no gain). Model: read-only ceiling ~3.1 TB/s
// (m13's 6.29 is read+write); residual gap = address locality.
// R10 = R9 fixed: __builtin_nontemporal_load needs ext_vector_type, not
// HIP float4/int4 structs. Levers: (1) XCD-chunked bijective block->row map;
// (2) nontemporal loads on streamed arrays; (3) x hoisted to regs, 2 rows/blk.

constexpr int IN_F  = 4096;
constexpr int OUT_F = 4096;
constexpr int NXCD  = 8;

typedef float v4f __attribute__((ext_vector_type(4)));
typedef int   v4i __attribute__((ext_vector_type(4)));

__device__ __forceinline__ float contrib(float w, int ii, int vi, float xf) {
    const float r  = (float)(__brev((unsigned)ii) >> 24);
    const float ri = (float)(__brev((unsigned)vi) >> 24);
    return (xf != 0.0f) ? ((w >= r) ? 1.0f : 0.0f)
                        : ((w >= ri) ? 0.0f : 1.0f);
}

__global__ __launch_bounds__(256, 4) void unary_linear_kernel(
    const float* __restrict__ x,            // [IN_F] in {0,1}
    const float* __restrict__ buf_wght,     // [OUT_F, IN_F]
    const float* __restrict__ buf_bias,     // [OUT_F]
    const float* __restrict__ acc,          // [OUT_F]
    const float* __restrict__ acc_bound,    // [1] = IN_F+1
    const int*   __restrict__ rng_wght_idx,     // [OUT_F, IN_F] in [0,256)
    const int*   __restrict__ rng_bias_idx,     // [OUT_F]
    const int*   __restrict__ rng_wght_idx_inv, // [OUT_F, IN_F]
    float*       __restrict__ out)          // [OUT_F]
{
    const int tid  = threadIdx.x;           // 0..255
    const int wave = tid >> 6;
    const int lane = tid & 63;

    // Bijective XCD-chunked mapping (grid=2048, 2048%8==0):
    // HW assigns blocks round-robin to XCDs, so xcd = blockIdx%8.
    // XCD k owns rows [k*512, (k+1)*512) -> one contiguous 24MB read slab
    // (3 arrays x 8MB) streamed through that XCD's private L2.
    const int xcd  = blockIdx.x & (NXCD - 1);
    const int slot = blockIdx.x >> 3;               // 0..255
    const int row0 = xcd * (OUT_F / NXCD) + slot * 2;

    __shared__ float wsum[4];

    // Hoist row-invariant x (16 elems/thread) — cached loads (reused chip-wide).
    v4f xv[4];
    #pragma unroll
    for (int i = 0; i < 4; ++i)
        xv[i] = *reinterpret_cast<const v4f*>(x + (i * 256 + tid) * 4);

    #pragma unroll
    for (int rr = 0; rr < 2; ++rr) {
        const int row = row0 + rr;
        const float* __restrict__ wrow = buf_wght         + (size_t)row * IN_F;
        const int*   __restrict__ irow = rng_wght_idx     + (size_t)row * IN_F;
        const int*   __restrict__ vrow = rng_wght_idx_inv + (size_t)row * IN_F;

        float sum = 0.0f;
        #pragma unroll
        for (int i = 0; i < 4; ++i) {
            const int base = (i * 256 + tid) * 4;   // coalesced 16B/lane
            const v4f w  = __builtin_nontemporal_load(
                               reinterpret_cast<const v4f*>(wrow + base));
            const v4i ii = __builtin_nontemporal_load(
                               reinterpret_cast<const v4i*>(irow + base));
            const v4i vi = __builtin_nontemporal_load(
                               reinterpret_cast<const v4i*>(vrow + base));
            sum += contrib(w.x, ii.x, vi.x, xv[i].x)
                 + contrib(w.y, ii.y, vi.y, xv[i].y)
                 + contrib(w.z, ii.z, vi.z, xv[i].z)
                 + contrib(w.w, ii.w, vi.w, xv[i].w);
        }

        // wave butterfly reduce (64 lanes)
        #pragma unroll
        for (int off = 32; off > 0; off >>= 1)
            sum += __shfl_down(sum, off);

        if (lane == 0) wsum[wave] = sum;
        __syncthreads();
        if (tid == 0) {
            const float rb = (float)(__brev((unsigned)rng_bias_idx[row]) >> 24);
            const float b_bit = (buf_bias[row] >= rb) ? 1.0f : 0.0f;
            const float total = acc[row] + wsum[0] + wsum[1] + wsum[2] + wsum[3] + b_bit;
            out[row] = (total >= acc_bound[0]) ? 1.0f : 0.0f;
        }
        __syncthreads();   // wsum reused next row
    }
}

extern "C" void kernel_launch(void* const* d_in, const int* in_sizes, int n_in,
                              void* d_out, int out_size, void* d_ws, size_t ws_size,
                              hipStream_t stream)
{
    // setup_inputs() order:
    // 0:x 1:buf_wght 2:buf_bias 3:rng 4:acc 5:acc_bound
    // 6:rng_wght_idx 7:rng_bias_idx 8:rng_wght_idx_inv
    const float* x         = (const float*)d_in[0];
    const float* buf_wght  = (const float*)d_in[1];
    const float* buf_bias  = (const float*)d_in[2];
    // d_in[3] = rng table — unused (closed form: rng[i] == bitreverse8(i))
    const float* acc       = (const float*)d_in[4];
    const float* acc_bound = (const float*)d_in[5];
    const int*   rwi       = (const int*)d_in[6];
    const int*   rbi       = (const int*)d_in[7];
    const int*   rwii      = (const int*)d_in[8];
    float* out = (float*)d_out;

    dim3 grid(2048);        // 2 rows/block; 2048%8==0 -> bijective XCD chunks
    dim3 block(256);
    hipLaunchKernelGGL(unary_linear_kernel, grid, block, 0, stream,
                       x, buf_wght, buf_bias, acc, acc_bound,
                       rwi, rbi, rwii, out);
}